// Round 13
// baseline (115.004 us; speedup 1.0000x reference)
//
#include <hip/hip_runtime.h>
#include <stdint.h>

// DILATE loss, B=32, L=512, DIM=16, gamma=1e-3, alpha=0.5.
//
// Round-13 = R12 structure with the LOAD PATH bisected back to proven parts:
//   - 4-wave pipelined wavefront per batch (R10, absmax 0.0 validated)
//   - 16-slot asm load pipeline w/ counted vmcnt (R11, absmax 0.0 validated)
//   - skewed D layout Dsk[s=j+i/2][i] (lane-uniform wave-step address)
//   - loads: asm global_load_dwordx2 "v"(voffset)+"s"(base) [R11's exact
//     proven form], voffset CLAMPED to [0, STRF*4-8] (no SRD, no OOB tricks
//     -- R12's hand-built SRD/buffer path was the only unvalidated piece)
//   - fmaxf(D,0) guard restored (R10); capture unconditional (R10).
// Junk cells read clamped/unwritten data d in [-3e-13, ~250]:
//   R_junk = d + 1e10 rounds to EXACTLY 1e10 (ulp(1e10)=1024) = reference
//   border; junk parents never beat real cells (<=~2.3e4). Inert.
//
//   kA : Dsk[b][s][i], s = j + i/2.
//   kP : one 256-thread block (4 waves). Lane tid owns rows {2tid,2tid+1};
//        col c = t - tid - 32w at step t (864 steps). Within-wave boundary:
//        DPP wave_shr. Cross-wave: 64-slot LDS ring, lgkm-only barrier every
//        16 steps (write precedes read by 33 steps; >=1 barrier between).
//        T[i,j] = T[argmin parent] + (i-j)^2, priority diag > up > left.
//   kC : combine -> scalar loss.

#define N 512
#define NB 32
#define BIGF 1e10f
#define NSK 768                   // skewed cols allocated (need 767)
#define STRF ((size_t)NSK * N)    // floats per batch
#define NBLK 54                   // 54*16 = 864 steps; last real t = 862
#define VOMAX ((int)(STRF * 4 - 8))

typedef unsigned int u32;
typedef unsigned long long u64;
typedef float f32x4 __attribute__((ext_vector_type(4)));
typedef float f32x2 __attribute__((ext_vector_type(2)));

__device__ __forceinline__ float dppshr(float x, float oldv) {
    // lane l gets lane l-1's x; lane 0 keeps oldv (bound_ctrl=false)
    return __int_as_float(__builtin_amdgcn_update_dpp(
        __float_as_int(oldv), __float_as_int(x), 0x138, 0xF, 0xF, false));
}

// ---------------- kA: pairwise squared distances -> skewed layout ----------
__global__ __launch_bounds__(512) void kA(const float* __restrict__ inp,
                                          const float* __restrict__ tgt,
                                          float* __restrict__ Dg) {
    const int b = blockIdx.y;
    const int jc = blockIdx.x;         // group of 4 columns
    const int tid = (int)threadIdx.x;  // row index i in [0,512)
    __shared__ float xs[4][16];        // x[j] = inp[b,j]-inp[b,0]
    if (tid < 64) {
        int c = tid >> 4, d = tid & 15;
        int j = jc * 4 + c;
        xs[c][d] = inp[(((size_t)b * N + j) << 4) + d] -
                   inp[(((size_t)b * N) << 4) + d];
    }
    __syncthreads();
    const float4* t4 = (const float4*)(tgt + (((size_t)b * N + tid) << 4));
    float4 ta = t4[0], tb = t4[1], tc = t4[2], td = t4[3];
    float* outB = Dg + (size_t)b * STRF;
    const int sh = tid >> 1;  // skew shift
#pragma unroll
    for (int c = 0; c < 4; ++c) {
        float s = 0.f, e;
        e = ta.x - xs[c][0];  s = fmaf(e, e, s);
        e = ta.y - xs[c][1];  s = fmaf(e, e, s);
        e = ta.z - xs[c][2];  s = fmaf(e, e, s);
        e = ta.w - xs[c][3];  s = fmaf(e, e, s);
        e = tb.x - xs[c][4];  s = fmaf(e, e, s);
        e = tb.y - xs[c][5];  s = fmaf(e, e, s);
        e = tb.z - xs[c][6];  s = fmaf(e, e, s);
        e = tb.w - xs[c][7];  s = fmaf(e, e, s);
        e = tc.x - xs[c][8];  s = fmaf(e, e, s);
        e = tc.y - xs[c][9];  s = fmaf(e, e, s);
        e = tc.z - xs[c][10]; s = fmaf(e, e, s);
        e = tc.w - xs[c][11]; s = fmaf(e, e, s);
        e = td.x - xs[c][12]; s = fmaf(e, e, s);
        e = td.y - xs[c][13]; s = fmaf(e, e, s);
        e = td.z - xs[c][14]; s = fmaf(e, e, s);
        e = td.w - xs[c][15]; s = fmaf(e, e, s);
        outB[(size_t)(jc * 4 + c + sh) * N + tid] = s;  // Dsk[j+i/2][i]
    }
}

// ---------------- kP: 4-wave pipelined wavefront DP ------------------------
__global__ __launch_bounds__(256) void kP(const float* __restrict__ Dg,
                                          float* __restrict__ acc) {
    const int b = blockIdx.x;
    const int tid = (int)threadIdx.x;
    const int w = tid >> 6, lam = tid & 63;
    const int off = tid + 32 * w;  // lane's step offset (= 96w + lam)
    const float* __restrict__ Db = Dg + (size_t)b * STRF;

    __shared__ __align__(16) f32x2 ring[3][64];
    __shared__ __align__(16) f32x2 dump[64];

    {
        f32x2 z; z.x = BIGF; z.y = 0.f;
        if (tid < 192) ((f32x2*)ring)[tid] = z;
        if (tid < 64) dump[tid] = z;
    }
    __syncthreads();

    // 16 load slots; slot k covers step t = k (mod 16);
    // voffset = (t - 32w)*2048 + tid*8, clamped to [0, VOMAX] at issue
    int vo0, vo1, vo2, vo3, vo4, vo5, vo6, vo7;
    int vo8, vo9, vo10, vo11, vo12, vo13, vo14, vo15;
    f32x2 d0, d1, d2, d3, d4, d5, d6, d7;
    f32x2 d8, d9, d10, d11, d12, d13, d14, d15;
    {
        const int vb = tid * 8 - 32 * w * 2048;
        vo0 = vb;            vo1 = vb + 2048;      vo2 = vb + 2 * 2048;
        vo3 = vb + 3 * 2048; vo4 = vb + 4 * 2048;  vo5 = vb + 5 * 2048;
        vo6 = vb + 6 * 2048; vo7 = vb + 7 * 2048;  vo8 = vb + 8 * 2048;
        vo9 = vb + 9 * 2048; vo10 = vb + 10 * 2048; vo11 = vb + 11 * 2048;
        vo12 = vb + 12 * 2048; vo13 = vb + 13 * 2048; vo14 = vb + 14 * 2048;
        vo15 = vb + 15 * 2048;
    }

#define LOAD(k)                                                               \
    do {                                                                      \
        int voc_ = min(max(vo##k, 0), VOMAX);                                 \
        asm volatile("global_load_dwordx2 %0, %1, %2"                         \
                     : "=v"(d##k) : "v"(voc_), "s"(Db));                      \
    } while (0)

    LOAD(0); LOAD(1); LOAD(2); LOAD(3); LOAD(4); LOAD(5); LOAD(6); LOAD(7);
    LOAD(8); LOAD(9); LOAD(10); LOAD(11); LOAD(12); LOAD(13); LOAD(14); LOAD(15);

    // DP state (R10 semantics verbatim)
    float Rp0 = BIGF, Rp1 = BIGF, Tp0 = 0.f, Tp1 = 0.f;
    float upR = BIGF, upT = 0.f;
    float dgR = (tid == 0) ? 0.f : BIGF, dgT = 0.f;
    float dr0 = (float)(2 * tid + off), dr1 = dr0 + 1.0f;
    int ci = -off;
    float Rfin = 0.f, Tfin = 0.f;

    const bool is_cons = (lam == 0) && (w > 0);
    f32x2* prodBase = ((lam == 63) && (w < 3)) ? &ring[w][0] : &dump[0];
    const f32x2* ringR = (w > 0) ? &ring[w - 1][0] : &ring[0][0];
    int rb = (-96 * w) & 63;

    f32x4 fA0, fA1, fA2, fA3, fB0, fB1, fB2, fB3;
    if (is_cons) {  // prime bank A (steps 0..7 handoff values)
        const f32x4* q = (const f32x4*)(ringR + rb);
        fA0 = q[0]; fA1 = q[1]; fA2 = q[2]; fA3 = q[3];
    }
    rb = (rb + 8) & 63;

#define STEP(k, FRV, FTV)                                                     \
    do {                                                                      \
        asm volatile("s_waitcnt vmcnt(15)" : "+v"(d##k));                     \
        float D0 = fmaxf(d##k.x, 0.f), D1 = fmaxf(d##k.y, 0.f);               \
        float mn0 = fminf(upR, fminf(dgR, Rp0));                              \
        float Ts0 = (mn0 == dgR) ? dgT : ((mn0 == upR) ? upT : Tp0);          \
        float R0 = D0 + mn0;                                                  \
        float T0 = fmaf(dr0, dr0, Ts0);                                       \
        float mn1 = fminf(R0, fminf(Rp0, Rp1));                               \
        float Ts1 = (mn1 == Rp0) ? Tp0 : ((mn1 == R0) ? T0 : Tp1);            \
        float R1 = D1 + mn1;                                                  \
        float T1 = fmaf(dr1, dr1, Ts1);                                       \
        bool hit = (ci == 511);                                               \
        Rfin = hit ? R1 : Rfin; Tfin = hit ? T1 : Tfin;                       \
        f32x2* wr = ((u32)ci < 512u) ? (prodBase + (ci & 63)) : (&dump[0] + lam); \
        f32x2 wv; wv.x = R1; wv.y = T1;                                       \
        *wr = wv;                                                             \
        Rp0 = R0; Tp0 = T0; Rp1 = R1; Tp1 = T1;                               \
        dgR = upR; dgT = upT;                                                 \
        float bR = dppshr(R1, BIGF), bT = dppshr(T1, 0.f);                    \
        upR = is_cons ? (FRV) : bR;                                           \
        upT = is_cons ? (FTV) : bT;                                           \
        dr0 -= 1.f; dr1 -= 1.f; ci += 1;                                      \
        vo##k += 32768; /* +16 skew-cols for this slot's next use */          \
        LOAD(k);                                                              \
    } while (0)

    for (int n = 0; n < NBLK; ++n) {
        asm volatile("s_waitcnt lgkmcnt(0)" ::: "memory");
        __builtin_amdgcn_s_barrier();
        // bank B: handoff for steps 16n+8 .. 16n+15
        if (is_cons) {
            const f32x4* q = (const f32x4*)(ringR + rb);
            fB0 = q[0]; fB1 = q[1]; fB2 = q[2]; fB3 = q[3];
        }
        rb = (rb + 8) & 63;
        STEP(0, fA0[2], fA0[3]); STEP(1, fA1[0], fA1[1]);
        STEP(2, fA1[2], fA1[3]); STEP(3, fA2[0], fA2[1]);
        STEP(4, fA2[2], fA2[3]); STEP(5, fA3[0], fA3[1]);
        STEP(6, fA3[2], fA3[3]); STEP(7, fB0[0], fB0[1]);
        // bank A: handoff for steps 16n+16 .. 16n+23
        if (is_cons) {
            const f32x4* q = (const f32x4*)(ringR + rb);
            fA0 = q[0]; fA1 = q[1]; fA2 = q[2]; fA3 = q[3];
        }
        rb = (rb + 8) & 63;
        STEP(8, fB0[2], fB0[3]);  STEP(9, fB1[0], fB1[1]);
        STEP(10, fB1[2], fB1[3]); STEP(11, fB2[0], fB2[1]);
        STEP(12, fB2[2], fB2[3]); STEP(13, fB3[0], fB3[1]);
        STEP(14, fB3[2], fB3[3]); STEP(15, fA0[0], fA0[1]);
    }
#undef STEP
#undef LOAD

    asm volatile("s_waitcnt vmcnt(0)" ::: "memory");  // drain before exit
    if (tid == 255) {
        acc[b] = Rfin;       // hard-DTW value Rp[N,N]
        acc[NB + b] = Tfin;  // sum (i-j)^2 along argmin path
    }
}

// ---------------- kC: combine over batches ---------------------------------
__global__ void kC(const float* __restrict__ acc, float* __restrict__ out) {
    const int l = (int)threadIdx.x;
    float vs = (l < NB) ? acc[l] : 0.f;
    float vt = (l < NB) ? acc[NB + l] : 0.f;
#pragma unroll
    for (int o = 32; o >= 1; o >>= 1) {
        vs += __shfl_down(vs, o);
        vt += __shfl_down(vt, o);
    }
    if (l == 0)
        out[0] = 0.5f * (vs / (float)NB) +
                 0.5f * (vt / ((float)NB * (float)(N * N)));
}

__global__ void kSentinel(float* out) { out[0] = -12345.0f; }

extern "C" void kernel_launch(void* const* d_in, const int* in_sizes, int n_in,
                              void* d_out, int out_size, void* d_ws, size_t ws_size,
                              hipStream_t stream) {
    const float* inp = (const float*)d_in[0];
    const float* tgt = (const float*)d_in[1];
    float* out = (float*)d_out;

    const size_t DSZ = (size_t)NB * STRF * sizeof(float);  // 48 MiB
    const size_t NEEDED = 256 + DSZ;
    if (ws_size < NEEDED) {
        kSentinel<<<1, 1, 0, stream>>>(out);
        return;
    }
    char* ws = (char*)d_ws;
    float* acc = (float*)ws;  // [0..31] shape, [32..63] temporal
    float* Dg = (float*)(ws + 256);

    kA<<<dim3(N / 4, NB), 512, 0, stream>>>(inp, tgt, Dg);
    kP<<<NB, 256, 0, stream>>>(Dg, acc);
    kC<<<1, 64, 0, stream>>>(acc, out);
}